// Round 8
// baseline (770.616 us; speedup 1.0000x reference)
//
#include <hip/hip_runtime.h>

// MoE ConvNeXt block: dwconv7x7 -> LN -> top2 router w/ capacity -> expert MLP (bf16 MFMA) -> combine
// Shapes: N=64 C=384 H=W=32 -> T=65536, E=8, K=2, Hd=1536, Be=13107, Bp=13184 (=103*128)
// R1-R6: sort machinery, fragment-linear barrier-free GEMMs. R7 failed (b128 conflicts intrinsic).
// R8: k_conv column-stacked b32 + 16-bit keys (2-pass sort). 856 -> 783us.
// R9 NULL: source-level double-buffer was undone by the compiler (VGPR 80->84, needs >=128 for two
//     live sets) -> loads re-sunk next to uses; latency theory untested.
// R10: force the pipeline: inline-asm global_load_dwordx4 into named bf16x8 sets, counted
//     s_waitcnt vmcnt(8) (set A complete while set B's 8 in flight), sched_barrier(0) after every
//     waitcnt and MFMA cluster (rule #18). VGPR should rise to ~160 - that's the codegen proof.
//     If dur still unchanged -> L2-BW-bound (20 TB/s measured), next is operand sharing.

typedef unsigned int u32;
typedef unsigned long long u64;
typedef unsigned short u16;
typedef __attribute__((ext_vector_type(8))) __bf16 bf16x8;
typedef __attribute__((ext_vector_type(4))) float f32x4;

#define T_TOK 65536
#define C_DIM 384
#define HD 1536
#define BE 13107
#define BP 13184

__device__ __forceinline__ u16 f2bf(float f) {
  u32 u = __float_as_uint(f);
  u32 r = (u + 0x7FFFu + ((u >> 16) & 1u)) >> 16;
  return (u16)r;
}
__device__ __forceinline__ float bf2f(u16 b) { return __uint_as_float(((u32)b) << 16); }

// RNE packed f32->bf16 pair (no builtin on gfx950)
__device__ __forceinline__ u32 cvtpk(float a, float b) {
  u32 r;
  asm("v_cvt_pk_bf16_f32 %0, %1, %2" : "=v"(r) : "v"(a), "v"(b));
  return r;
}

// forced async load: 16B/lane into a named 4-VGPR tuple; byte offset immediate.
#define GLD(dst, ptr, OFF)                                                    \
  asm volatile("global_load_dwordx4 %0, %1, off offset:" #OFF                 \
               : "=v"(dst) : "v"(ptr) : "memory")

// ---------------- depthwise conv 7x7 (one (n,c) plane per block) ----------------
// R8: column-stacked outputs; b32 column reads, 2 lanes/bank (free); weights off the LDS pipe.
__global__ __launch_bounds__(256) void k_conv(const float* __restrict__ x,
                                              const float* __restrict__ cw,
                                              const float* __restrict__ cb,
                                              float* __restrict__ hconv) {
  __shared__ float xp[38 * 38];  // padded plane [row 0..37][col 0..37], stride 38
  int b = blockIdx.x;            // n*384 + c
  int c = b % 384;
  int tid = threadIdx.x;
  float w49[49];
#pragma unroll
  for (int i = 0; i < 49; i++) w49[i] = cw[i * 384 + c];
  float bias = cb[c];
  for (int i = tid; i < 38 * 38; i += 256) xp[i] = 0.0f;
  __syncthreads();
  const float* xsrc = x + (size_t)b * 1024;
  {
    float4 v = *(const float4*)&xsrc[tid * 4];
    int yy = tid >> 3, xx = (tid & 7) * 4;
    float* d = &xp[(yy + 3) * 38 + xx + 3];
    d[0] = v.x; d[1] = v.y; d[2] = v.z; d[3] = v.w;
  }
  __syncthreads();
  int cl = tid & 31, r0 = (tid >> 5) << 2;
  float o0 = bias, o1 = bias, o2 = bias, o3 = bias;
  const float* colbase = &xp[r0 * 38 + cl];
#pragma unroll
  for (int kx = 0; kx < 7; kx++) {
    float v[10];
#pragma unroll
    for (int k = 0; k < 10; k++) v[k] = colbase[k * 38 + kx];
#pragma unroll
    for (int ky = 0; ky < 7; ky++) {
      float wt = w49[ky * 7 + kx];
      o0 += wt * v[ky + 0];
      o1 += wt * v[ky + 1];
      o2 += wt * v[ky + 2];
      o3 += wt * v[ky + 3];
    }
  }
  float* dst = &hconv[(size_t)b * 1024 + r0 * 32 + cl];
  dst[0] = o0;
  dst[32] = o1;
  dst[64] = o2;
  dst[96] = o3;
}

// ---------------- LayerNorm (over C) + bf16 cast ----------------
__global__ __launch_bounds__(256) void k_ln(const float* __restrict__ hconv,
                                            const float* __restrict__ lng,
                                            const float* __restrict__ lnb,
                                            u16* __restrict__ xln) {
  __shared__ float tile[384 * 33];
  int nb = blockIdx.x;              // n*32 + y
  int n = nb >> 5, y = nb & 31;
  int tid = threadIdx.x;
  const float* src = hconv + (size_t)n * 384 * 1024 + (y << 5);
  for (int i = tid; i < 12288; i += 256) {
    int c = i >> 5, w = i & 31;
    tile[c * 33 + w] = src[(size_t)c * 1024 + w];
  }
  __syncthreads();
  int wv = tid >> 6, lane = tid & 63;
  for (int w = wv; w < 32; w += 4) {
    float v[6];
    float s = 0.f, s2 = 0.f;
#pragma unroll
    for (int k = 0; k < 6; k++) {
      float t = tile[(lane + (k << 6)) * 33 + w];
      v[k] = t; s += t; s2 += t * t;
    }
#pragma unroll
    for (int off = 32; off > 0; off >>= 1) {
      s += __shfl_xor(s, off, 64);
      s2 += __shfl_xor(s2, off, 64);
    }
    float mu = s * (1.0f / 384.0f);
    float var = s2 * (1.0f / 384.0f) - mu * mu;
    float r = rsqrtf(var + 1e-6f);
    size_t t0 = ((size_t)nb << 5) + w;
#pragma unroll
    for (int k = 0; k < 6; k++) {
      int c = lane + (k << 6);
      float o = (v[k] - mu) * r * lng[c] + lnb[c];
      xln[t0 * 384 + c] = f2bf(o);
    }
  }
}

// ---------------- router: logits(8), top2 + gates; 16-bit priority key ----------------
__global__ __launch_bounds__(256) void k_router(const u16* __restrict__ xln,
                                                const float* __restrict__ gw,
                                                u32* __restrict__ keys, u32* __restrict__ vals,
                                                u32* __restrict__ topi,
                                                float* __restrict__ g1, float* __restrict__ g2) {
  __shared__ float gwl[8 * 384];
  int tid = threadIdx.x;
  for (int i = tid; i < 3072; i += 256) gwl[i] = gw[i];
  __syncthreads();
  int wv = tid >> 6, lane = tid & 63;
  int t = (blockIdx.x << 2) + wv;
  float acc[8] = {0, 0, 0, 0, 0, 0, 0, 0};
#pragma unroll
  for (int k = 0; k < 6; k++) {
    int c = lane + (k << 6);
    float xv = bf2f(xln[(size_t)t * 384 + c]);
#pragma unroll
    for (int e = 0; e < 8; e++) acc[e] += xv * gwl[e * 384 + c];
  }
#pragma unroll
  for (int off = 32; off > 0; off >>= 1) {
#pragma unroll
    for (int e = 0; e < 8; e++) acc[e] += __shfl_xor(acc[e], off, 64);
  }
  if (lane == 0) {
    float v1 = -1e30f, v2 = -1e30f;
    int e1 = 0, e2 = 0;
#pragma unroll
    for (int e = 0; e < 8; e++) {
      float l = acc[e];
      if (l > v1) { v2 = v1; e2 = e1; v1 = l; e1 = e; }
      else if (l > v2) { v2 = l; e2 = e; }
    }
    float sum = 0.f;
#pragma unroll
    for (int e = 0; e < 8; e++) sum += __expf(acc[e] - v1);
    float p = 1.0f / sum;
    float ew = __expf(v2 - v1);
    float w1 = 1.0f / (1.0f + ew);
    keys[t] = (~__float_as_uint(p)) >> 16;  // 16-bit key: ascending == descending priority
    vals[t] = (u32)t;
    topi[t] = (u32)e1 | ((u32)e2 << 8);
    g1[t] = w1;
    g2[t] = ew * w1;
  }
}

// ---------------- stable counting-sort machinery (8-bit digit) ----------------
__global__ __launch_bounds__(256) void k_hist(const u32* __restrict__ keys,
                                              u32* __restrict__ hist, int shift) {
  __shared__ u32 h[256];
  int tid = threadIdx.x;
  h[tid] = 0;
  __syncthreads();
  u32 key = keys[((size_t)blockIdx.x << 8) + tid];
  atomicAdd(&h[(key >> shift) & 255u], 1u);
  __syncthreads();
  hist[(size_t)tid * gridDim.x + blockIdx.x] = h[tid];
}

__global__ __launch_bounds__(256) void k_scan_rows(u32* __restrict__ data,
                                                   u32* __restrict__ totals, int nb) {
  __shared__ u32 ws[256];
  int d = blockIdx.x, tid = threadIdx.x;
  int seg = nb >> 8;
  u32 base = (u32)d * nb + tid * seg;
  u32 v[2] = {0, 0};
  u32 s = 0;
  for (int i = 0; i < seg; i++) { v[i] = data[base + i]; s += v[i]; }
  ws[tid] = s;
  __syncthreads();
  for (int dd = 1; dd < 256; dd <<= 1) {
    u32 t = (tid >= dd) ? ws[tid - dd] : 0u;
    __syncthreads();
    ws[tid] += t;
    __syncthreads();
  }
  if (tid == 255) totals[d] = ws[255];
  u32 run = (tid > 0) ? ws[tid - 1] : 0u;
  for (int i = 0; i < seg; i++) {
    u32 tmp = v[i];
    data[base + i] = run;
    run += tmp;
  }
}

__global__ __launch_bounds__(256) void k_scan_digits(const u32* __restrict__ totals,
                                                     u32* __restrict__ dbase) {
  __shared__ u32 ws[256];
  int tid = threadIdx.x;
  ws[tid] = totals[tid];
  __syncthreads();
  for (int dd = 1; dd < 256; dd <<= 1) {
    u32 t = (tid >= dd) ? ws[tid - dd] : 0u;
    __syncthreads();
    ws[tid] += t;
    __syncthreads();
  }
  dbase[tid] = (tid > 0) ? ws[tid - 1] : 0u;
}

__global__ __launch_bounds__(256) void k_scatter(const u32* __restrict__ kin,
                                                 const u32* __restrict__ vin,
                                                 u32* __restrict__ kout, u32* __restrict__ vout,
                                                 const u32* __restrict__ scanned,
                                                 const u32* __restrict__ dbase, int shift) {
  __shared__ u32 cnt[4 * 256];
  int tid = threadIdx.x;
  int w = tid >> 6, l = tid & 63;
  int g = (blockIdx.x << 8) + tid;
  u32 key = kin[g], val = vin[g];
  u32 d = (key >> shift) & 255u;
  for (int i = tid; i < 1024; i += 256) cnt[i] = 0u;
  __syncthreads();
  u64 match = ~0ull;
#pragma unroll
  for (int b = 0; b < 8; b++) {
    int bit = (d >> b) & 1;
    u64 bal = __ballot(bit);
    match &= bit ? bal : ~bal;
  }
  u32 rw = __popcll(match & ((1ull << l) - 1ull));
  if (rw == 0) cnt[(w << 8) + d] = (u32)__popcll(match);
  __syncthreads();
  u32 pre = 0;
  for (int w2 = 0; w2 < w; w2++) pre += cnt[(w2 << 8) + d];
  u32 pos = dbase[d] + scanned[(size_t)d * gridDim.x + blockIdx.x] + pre + rw;
  kout[pos] = key;
  vout[pos] = val;
}

__global__ __launch_bounds__(256) void k_entries(const u32* __restrict__ order,
                                                 const u32* __restrict__ topi,
                                                 const float* __restrict__ g1,
                                                 const float* __restrict__ g2,
                                                 u32* __restrict__ ee, u32* __restrict__ et,
                                                 float* __restrict__ eg) {
  int m = (blockIdx.x << 8) + threadIdx.x;
  int i = m & 65535, k = m >> 16;
  u32 tok = order[i];
  u32 pk = topi[tok];
  ee[m] = k ? ((pk >> 8) & 255u) : (pk & 255u);
  et[m] = tok;
  eg[m] = k ? g2[tok] : g1[tok];
}

__global__ __launch_bounds__(256) void k_dispatch(const u32* __restrict__ ee,
                                                  const u32* __restrict__ et,
                                                  const float* __restrict__ eg,
                                                  const u32* __restrict__ scanned,
                                                  int* __restrict__ dtok, float* __restrict__ dgate,
                                                  int* __restrict__ inv) {
  __shared__ u32 cnt[4 * 8];
  int tid = threadIdx.x;
  int w = tid >> 6, l = tid & 63;
  int m = (blockIdx.x << 8) + tid;
  u32 e = ee[m];
  if (tid < 32) cnt[tid] = 0u;
  __syncthreads();
  u64 match = ~0ull;
#pragma unroll
  for (int b = 0; b < 3; b++) {
    int bit = (e >> b) & 1;
    u64 bal = __ballot(bit);
    match &= bit ? bal : ~bal;
  }
  u32 rw = __popcll(match & ((1ull << l) - 1ull));
  if (rw == 0) cnt[(w << 3) + e] = (u32)__popcll(match);
  __syncthreads();
  u32 pre = 0;
  for (int w2 = 0; w2 < w; w2++) pre += cnt[(w2 << 3) + e];
  u32 pos = scanned[(size_t)e * gridDim.x + blockIdx.x] + pre + rw;
  if (pos < (u32)BE) {
    int slot = (int)e * BP + (int)pos;
    dtok[slot] = (int)et[m];
    dgate[slot] = eg[m];
    inv[et[m] * 2 + (m >> 16)] = slot;
  }
}

// ---------------- weight pre-pack: w [E][NKK*32][S] fp32 -> wp [e][by][kk][slot 512][8] bf16 ----
__global__ __launch_bounds__(256) void k_pack(const float* __restrict__ w,
                                              u16* __restrict__ wp, int NKK, int S) {
  __shared__ float tile[32 * 132];
  int e = blockIdx.y;
  int bx = blockIdx.x;
  int by = bx / NKK, kk = bx - by * NKK;
  int tid = threadIdx.x;
  const float* src = w + ((size_t)e * NKK * 32 + (size_t)kk * 32) * S + by * 128;
  for (int i = tid; i < 4096; i += 256) {
    int r = i >> 7, c = i & 127;
    tile[r * 132 + c] = src[(size_t)r * S + c];
  }
  __syncthreads();
  u16* dst = wp + ((size_t)e * gridDim.x + bx) * 4096;
#pragma unroll
  for (int h = 0; h < 2; h++) {
    int f = tid + (h << 8);
    int lane6 = f & 63, grp = f >> 6;
    int m15 = lane6 & 15, kq = lane6 >> 4;
    u16 o[8];
#pragma unroll
    for (int j = 0; j < 8; j++) o[j] = f2bf(tile[(kq * 8 + j) * 132 + grp * 16 + m15]);
    *(uint4*)&dst[f * 8] = *(const uint4*)o;
  }
}

// ---------------- A gather+pack for gemm1: apack [zloc][bx][kk 12][slot 512][8] ----------------
__global__ __launch_bounds__(256) void k_gather(const u16* __restrict__ xln,
                                                const int* __restrict__ dtok,
                                                u16* __restrict__ apack, int e0) {
  __shared__ int stok[128];
  int b = blockIdx.x;        // zloc*103 + bx
  int zloc = b / 103, bx = b - zloc * 103;
  int e = e0 + zloc;
  int tid = threadIdx.x;
  if (tid < 128) stok[tid] = dtok[e * BP + bx * 128 + tid];
  __syncthreads();
  u16* dst = apack + (size_t)b * 12 * 4096;
  int f0 = tid, f1 = tid + 256;
  int g0 = f0 >> 6, l0 = f0 & 63;
  int g1 = f1 >> 6, l1 = f1 & 63;
  int tokA = stok[g0 * 16 + (l0 & 15)];
  int tokB = stok[g1 * 16 + (l1 & 15)];
  const u16* sA = xln + (size_t)tokA * 384 + (l0 >> 4) * 8;
  const u16* sB = xln + (size_t)tokB * 384 + (l1 >> 4) * 8;
  u16* dA = dst + f0 * 8;
  u16* dB = dst + f1 * 8;
#pragma unroll
  for (int kk = 0; kk < 12; kk++) {
    *(uint4*)(dA + kk * 4096) = *(const uint4*)(sA + kk * 32);
    *(uint4*)(dB + kk * 4096) = *(const uint4*)(sB + kk * 32);
  }
}

// MFMA cluster macro (shared by both GEMMs): setprio + sched_barrier fences.
#define MMCL(A_, B_)                                                         \
  {                                                                          \
    __builtin_amdgcn_s_setprio(1);                                           \
    _Pragma("unroll") for (int i = 0; i < 4; i++)                            \
        _Pragma("unroll") for (int j = 0; j < 4; j++)                        \
            acc[i][j] = __builtin_amdgcn_mfma_f32_16x16x32_bf16(             \
                B_[j], A_[i], acc[i][j], 0, 0, 0);                           \
    __builtin_amdgcn_s_setprio(0);                                           \
  }
#define LDSET(AF, BF, pa, pb)                                                \
  {                                                                          \
    GLD(AF[0], pa, 0); GLD(AF[1], pa, 1024);                                 \
    GLD(AF[2], pa, 2048); GLD(AF[3], pa, 3072);                              \
    GLD(BF[0], pb, 0); GLD(BF[1], pb, 1024);                                 \
    GLD(BF[2], pb, 2048); GLD(BF[3], pb, 3072);                              \
  }
#define WAITV8                                                               \
  asm volatile("s_waitcnt vmcnt(8)" ::: "memory");                           \
  __builtin_amdgcn_sched_barrier(0);
#define WAITV0                                                               \
  asm volatile("s_waitcnt vmcnt(0)" ::: "memory");                           \
  __builtin_amdgcn_sched_barrier(0);
#define FENCE __builtin_amdgcn_sched_barrier(0);

// ---------------- GEMM1: hid_pack = pack(gelu(A @ w1 + b1)) ----------------
// Barrier-free; R10: forced asm pipeline, 2 sets, vmcnt(8) steady state.
__global__ __launch_bounds__(256) void k_gemm1(const u16* __restrict__ apack,
                                               const u16* __restrict__ w1p,
                                               const float* __restrict__ b1,
                                               u16* __restrict__ hid, int e0) {
  __shared__ u16 rpw[4 * 4608];   // per-wave [64][72] repack, no barriers
  int tid = threadIdx.x;
  int bid = blockIdx.x;
  // chunked bijective XCD swizzle (nwg=4944=8*618): z outer, bx, by fastest
  int lg = (bid & 7) * 618 + (bid >> 3);
  int z = lg / 1236;
  int rr = lg - z * 1236;
  int bx = rr / 12;
  int by = rr - bx * 12;
  int e = e0 + z;
  int wv = tid >> 6, lane = tid & 63;
  int wm = wv & 1, wn = wv >> 1;
  int quad = lane >> 4, c15 = lane & 15;
  const u16* ap = apack + ((size_t)(z * 103 + bx) * 12) * 4096 + (wm * 4) * 512 + lane * 8;
  const u16* bp = w1p + ((size_t)(e * 12 + by) * 12) * 4096 + (wn * 4) * 512 + lane * 8;
  float4 bias4[4];
#pragma unroll
  for (int j = 0; j < 4; j++)
    bias4[j] = *(const float4*)&b1[e * HD + by * 128 + wn * 64 + j * 16 + quad * 4];
  f32x4 acc[4][4];
#pragma unroll
  for (int i = 0; i < 4; i++)
#pragma unroll
    for (int j = 0; j < 4; j++) acc[i][j] = (f32x4){0.f, 0.f, 0.f, 0.f};

  bf16x8 afA[4], bfA[4], afB[4], bfB[4];
  const u16* pa1 = ap;
  const u16* pb1 = bp;
  const u16* pa2 = ap + 4096;
  const u16* pb2 = bp + 4096;
  LDSET(afA, bfA, pa1, pb1)          // kk 0   (8 in flight)
  LDSET(afB, bfB, pa2, pb2)          // kk 1   (16 in flight)
  for (int t = 0; t < 5; t++) {
    WAITV8                            // set A (kk 2t) done
    MMCL(afA, bfA)
    FENCE
    pa1 += 8192; pb1 += 8192;
    LDSET(afA, bfA, pa1, pb1)        // kk 2t+2
    WAITV8                            // set B (kk 2t+1) done
    MMCL(afB, bfB)
    FENCE
    pa2 += 8192; pb2 += 8192;
    LDSET(afB, bfB, pa2, pb2)        // kk 2t+3
  }
  WAITV8
  MMCL(afA, bfA)                      // kk 10
  WAITV0
  MMCL(afB, bfB)                      // kk 11

  // wave-private epilogue: bias + rcp-gelu + cvt_pk -> [64][72] repack -> pack-layout stores
  u16* prp = &rpw[wv * 4608];
#pragma unroll
  for (int j = 0; j < 4; j++) {
    float4 b4 = bias4[j];
    int ncol = j * 16 + quad * 4;
#pragma unroll
    for (int i = 0; i < 4; i++) {
      int mrow = i * 16 + c15;
      float v0 = acc[i][j][0] + b4.x;
      float v1 = acc[i][j][1] + b4.y;
      float v2 = acc[i][j][2] + b4.z;
      float v3 = acc[i][j][3] + b4.w;
      v0 *= __builtin_amdgcn_rcpf(1.0f + __expf(-1.702f * v0));
      v1 *= __builtin_amdgcn_rcpf(1.0f + __expf(-1.702f * v1));
      v2 *= __builtin_amdgcn_rcpf(1.0f + __expf(-1.702f * v2));
      v3 *= __builtin_amdgcn_rcpf(1.0f + __expf(-1.702f * v3));
      uint2 pk;
      pk.x = cvtpk(v0, v1);
      pk.y = cvtpk(v2, v3);
      *(uint2*)&prp[mrow * 72 + ncol] = pk;
    }
  }
  // hid pack layout: [z][bx][kk2 48][g 8][lane 64][8]
  u16* hb = hid + ((size_t)(z * 103 + bx) * 48 + by * 4 + wn * 2) * 4096 + (wm * 4) * 512 + lane * 8;
#pragma unroll
  for (int k2 = 0; k2 < 2; k2++)
#pragma unroll
    for (int gs = 0; gs < 4; gs++) {
      uint4 v = *(const uint4*)&prp[(gs * 16 + c15) * 72 + k2 * 32 + quad * 8];
      *(uint4*)(hb + (size_t)k2 * 4096 + gs * 512) = v;
    }
}

// ---------------- GEMM2: y = (hid @ w2 + b2) * gate (row-major bf16 out) ----------------
// R10: forced asm pipeline (48 K-steps).
__global__ __launch_bounds__(256) void k_gemm2(const u16* __restrict__ hid,
                                               const u16* __restrict__ w2p,
                                               const float* __restrict__ b2,
                                               const float* __restrict__ dgate,
                                               u16* __restrict__ yb, int e0) {
  __shared__ u16 rpw[4 * 4608];
  int tid = threadIdx.x;
  int bid = blockIdx.x;
  // bijective chunked XCD swizzle: nwg=1236, q=154, rem=4
  int xcd = bid & 7;
  int lg = xcd * 154 + (xcd < 4 ? xcd : 4) + (bid >> 3);
  int z = lg / 309;
  int rr = lg - z * 309;
  int bx = rr / 3;
  int byn = rr - bx * 3;
  int e = e0 + z;
  int wv = tid >> 6, lane = tid & 63;
  int wm = wv & 1, wn = wv >> 1;
  int quad = lane >> 4, c15 = lane & 15;
  const u16* ap = hid + ((size_t)(z * 103 + bx) * 48) * 4096 + (wm * 4) * 512 + lane * 8;
  const u16* bp = w2p + ((size_t)(e * 3 + byn) * 48) * 4096 + (wn * 4) * 512 + lane * 8;
  float4 bias4[4];
#pragma unroll
  for (int j = 0; j < 4; j++)
    bias4[j] = *(const float4*)&b2[e * 384 + byn * 128 + wn * 64 + j * 16 + quad * 4];
  float gv[4];
#pragma unroll
  for (int i = 0; i < 4; i++) gv[i] = dgate[e * BP + bx * 128 + wm * 64 + i * 16 + c15];
  f32x4 acc[4][4];
#pragma unroll
  for (int i = 0; i < 4; i++)
#pragma unroll
    for (int j = 0; j < 4; j++) acc[i][j] = (f32x4){0.f, 0.f, 0.f, 0.f};

  bf16x8 afA[4], bfA[4], afB[4], bfB[4];
  const u16* pa1 = ap;
  const u16* pb1 = bp;
  const u16* pa2 = ap + 4096;
  const u16* pb2 = bp + 4096;
  LDSET(afA, bfA, pa1, pb1)          // kk 0
  LDSET(afB, bfB, pa2, pb2)          // kk 1
  for (int t = 0; t < 23; t++) {
    WAITV8
    MMCL(afA, bfA)
    FENCE
    pa1 += 8192; pb1 += 8192;
    LDSET(afA, bfA, pa1, pb1)        // kk 2t+2
    WAITV8
    MMCL(afB, bfB)
    FENCE
    pa2 += 8192; pb2 += 8192;
    LDSET(afB, bfB, pa2, pb2)        // kk 2t+3
  }
  WAITV8
  MMCL(afA, bfA)                      // kk 46
  WAITV0
  MMCL(afB, bfB)                      // kk 47

  // wave-private epilogue: bias + gate -> [64][72] -> coalesced row-major stores (128B/row)
  u16* prp = &rpw[wv * 4608];
#pragma unroll
  for (int j = 0; j < 4; j++) {
    float4 b4 = bias4[j];
    int ncol = j * 16 + quad * 4;
#pragma unroll
    for (int i = 0; i < 4; i++) {
      int mrow = i * 16 + c15;
      float g = gv[i];
      float v0 = (acc[i][j][0] + b4.x) * g;
      float v1 = (acc[i][j][1] + b4.y) * g;
      float v2 = (acc[i][j][2] + b4.z) * g;
      float v3 = (acc[i][j][3] + b4.w) * g;
      uint2 pk;
      pk.x = cvtpk(v0, v1);
      pk.y = cvtpk(v2, v3);
      *(uint2*)&prp[mrow * 72 + ncol] = pk;
    }
  }
  u16* ybase = yb + ((size_t)(e * BP + bx * 128 + wm * 64)) * 384 + byn * 128 + wn * 64;
#pragma unroll
  for (int it = 0; it < 8; it++) {
    int r = it * 8 + (lane >> 3);
    int n0 = (lane & 7) * 8;
    uint4 v = *(const uint4*)&prp[r * 72 + n0];
    *(uint4*)(ybase + (size_t)r * 384 + n0) = v;
  }
}

// ---------------- combine: out = x + ls * (gathered y rows), NHWC->NCHW via LDS ----------------
__global__ __launch_bounds__(256) void k_final(const float* __restrict__ x,
                                               const u16* __restrict__ yb,
                                               const int* __restrict__ inv,
                                               const float* __restrict__ ls,
                                               float* __restrict__ out) {
  __shared__ float tile[32 * 385];
  __shared__ int sl[64];
  int nb = blockIdx.x;  // n*32 + y
  int n = nb >> 5, yy = nb & 31;
  int tid = threadIdx.x;
  int t0 = nb << 5;
  if (tid < 64) sl[tid] = inv[t0 * 2 + tid];
  __syncthreads();
  for (int idx = tid; idx < 1536; idx += 256) {
    int w = idx / 48;
    int cc = (idx - w * 48) << 3;
    float a[8] = {0, 0, 0, 0, 0, 0, 0, 0};
#pragma unroll
    for (int k = 0; k < 2; k++) {
      int s = sl[(w << 1) + k];
      if (s >= 0) {
        uint4 v = *(const uint4*)&yb[(size_t)s * 384 + cc];
        const u16* pv = (const u16*)&v;
#pragma unroll
        for (int j = 0; j < 8; j++) a[j] += bf2f(pv[j]);
      }
    }
    float* tp = &tile[w * 385 + cc];
#pragma unroll
    for (int j = 0; j < 8; j++) tp[j] = a[j];
  }
  __syncthreads();
  for (int i2 = tid; i2 < 3072; i2 += 256) {
    int c = i2 >> 3, w4 = (i2 & 7) << 2;
    size_t o = ((((size_t)n * 384 + c) << 5) + yy) * 32 + w4;
    float4 xv = *(const float4*)&x[o];
    float lsv = ls[c];
    float4 r;
    r.x = xv.x + lsv * tile[(w4 + 0) * 385 + c];
    r.y = xv.y + lsv * tile[(w4 + 1) * 385 + c];
    r.z = xv.z + lsv * tile[(w4 + 2) * 385 + c];
    r.w = xv.w + lsv * tile[(w4 + 3) * 385 + c];
    *(float4*)&out[o] = r;
  }
}

extern "C" void kernel_launch(void* const* d_in, const int* in_sizes, int n_in,
                              void* d_out, int out_size, void* d_ws, size_t ws_size,
                              hipStream_t stream) {
  (void)in_sizes; (void)n_in; (void)out_size; (void)ws_size;
  const float* x     = (const float*)d_in[0];
  const float* convw = (const float*)d_in[1];
  const float* convb = (const float*)d_in[2];
  const float* lng   = (const float*)d_in[3];
  const float* lnb   = (const float*)d_in[4];
  const float* gw    = (const float*)d_in[5];
  const float* w1    = (const float*)d_in[6];
  const float* b1    = (const float*)d_in[7];
  const float* w2    = (const float*)d_in[8];
  const float* b2    = (const float*)d_in[9];
  const float* ls    = (const float*)d_in[10];
  float* out = (float*)d_out;

  char* p = (char*)d_ws;
  size_t o = 0;
  auto alloc = [&](size_t b) { void* r = p + o; o += (b + 255) & ~(size_t)255; return r; };
  u16* xln    = (u16*)alloc((size_t)T_TOK * C_DIM * 2);          // 50.3 MB
  u16* w1p    = (u16*)alloc((size_t)8 * 144 * 4096 * 2);         // 9.4 MB  [e][by12][kk12][512][8]
  u16* w2p    = (u16*)alloc((size_t)8 * 144 * 4096 * 2);         // 9.4 MB  [e][byn3][kk48][512][8]
  u16* hid    = (u16*)alloc((size_t)4 * BP * HD * 2);            // 162 MB pack layout (+conv alias)
  u16* yb     = (u16*)alloc((size_t)8 * BP * 384 * 2);           // 81 MB
  u16* apack  = (u16*)alloc((size_t)4 * 103 * 12 * 4096 * 2);    // 40.5 MB [zloc][bx][kk][512][8]
  u32* keysA  = (u32*)alloc((size_t)T_TOK * 4);
  u32* keysB  = (u32*)alloc((size_t)T_TOK * 4);
  u32* valsA  = (u32*)alloc((size_t)T_TOK * 4);
  u32* valsB  = (u32*)alloc((size_t)T_TOK * 4);
  u32* topi   = (u32*)alloc((size_t)T_TOK * 4);
  float* g1   = (float*)alloc((size_t)T_TOK * 4);
  float* g2   = (float*)alloc((size_t)T_TOK * 4);
  u32* hist   = (u32*)alloc((size_t)256 * 512 * 4);
  u32* totals = (u32*)alloc((size_t)256 * 4);
  u32* dbase  = (u32*)alloc((size_t)256 * 4);
  u32* ee     = (u32*)alloc((size_t)131072 * 4);
  u32* et     = (u32*)alloc((size_t)131072 * 4);
  float* eg   = (float*)alloc((size_t)131072 * 4);
  int* dtok   = (int*)alloc((size_t)8 * BP * 4);
  float* dgate= (float*)alloc((size_t)8 * BP * 4);
  int* inv    = (int*)alloc((size_t)T_TOK * 2 * 4);

  float* hconv = (float*)hid;  // alias: conv output consumed by k_ln before GEMM1 writes hid

  k_conv<<<24576, 256, 0, stream>>>(x, convw, convb, hconv);
  k_ln<<<2048, 256, 0, stream>>>(hconv, lng, lnb, xln);
  k_router<<<16384, 256, 0, stream>>>(xln, gw, keysA, valsA, topi, g1, g2);

  // stable radix sort on 16-bit truncated priority keys: 2 x 8-bit passes, ends back in keysA/valsA
  u32 *ki = keysA, *vi = valsA, *ko = keysB, *vo = valsB;
  for (int pass = 0; pass < 2; pass++) {
    int shift = pass * 8;
    k_hist<<<256, 256, 0, stream>>>(ki, hist, shift);
    k_scan_rows<<<256, 256, 0, stream>>>(hist, totals, 256);
    k_scan_digits<<<1, 256, 0, stream>>>(totals, dbase);
    k_scatter<<<256, 256, 0, stream>>>(ki, vi, ko, vo, hist, dbase, shift);
    u32* t1 = ki; ki = ko; ko = t1;
    u32* t2 = vi; vi = vo; vo = t2;
  }
  k_entries<<<512, 256, 0, stream>>>(vi, topi, g1, g2, ee, et, eg);
  k_hist<<<512, 256, 0, stream>>>(ee, hist, 0);
  k_scan_rows<<<256, 256, 0, stream>>>(hist, totals, 512);
  hipMemsetAsync(dtok, 0, (size_t)8 * BP * 4, stream);
  hipMemsetAsync(dgate, 0, (size_t)8 * BP * 4, stream);
  hipMemsetAsync(inv, 0xFF, (size_t)T_TOK * 2 * 4, stream);
  k_dispatch<<<512, 256, 0, stream>>>(ee, et, eg, hist, dtok, dgate, inv);

  // fragment-linear weight packs (one-time)
  k_pack<<<dim3(144, 8), 256, 0, stream>>>(w1, w1p, 12, 1536);
  k_pack<<<dim3(144, 8), 256, 0, stream>>>(w2, w2p, 48, 384);

  for (int g = 0; g < 2; g++) {
    k_gather<<<412, 256, 0, stream>>>(xln, dtok, apack, g * 4);
    k_gemm1<<<4944, 256, 0, stream>>>(apack, w1p, b1, hid, g * 4);
    k_gemm2<<<1236, 256, 0, stream>>>(hid, w2p, b2, dgate, yb, g * 4);
  }
  k_final<<<2048, 256, 0, stream>>>(x, yb, inv, ls, out);
}

// Round 10
// 712.228 us; speedup vs baseline: 1.0820x; 1.0820x over previous
//
#include <hip/hip_runtime.h>

// MoE ConvNeXt block: dwconv7x7 -> LN -> top2 router w/ capacity -> expert MLP (bf16 MFMA) -> combine
// Shapes: N=64 C=384 H=W=32 -> T=65536, E=8, K=2, Hd=1536, Be=13107, Bp=13184 (=103*128)
// R1-R8: sort machinery, fragment-linear barrier-free GEMMs, conv b32 columns, 2-pass sort. 783us.
// R9/R10 NULL: reg double-buffer (source + forced asm) -> k_gemm2 stuck ~89us. Verdict: per-CU
//     request/byte throughput, 2x operand redundancy (each frag fetched by 2 waves).
// R11: LDS broadcast staging, fragment-linear (contiguous 1KB per global_load_lds), 3 buffers,
//     counted vmcnt(8), raw barriers. CRASHED once on a node with pathological push times (601s);
//     full audit found no intrinsic fault (addresses in-bounds, protocol == R3 which passed).
// R12: resubmit R11 + hardening: sched_barrier(0) after every inline-asm waitcnt. Pre-commit:
//     second crash => intrinsic => revert GEMMs to R8 next round.

typedef unsigned int u32;
typedef unsigned long long u64;
typedef unsigned short u16;
typedef __attribute__((ext_vector_type(8))) __bf16 bf16x8;
typedef __attribute__((ext_vector_type(4))) float f32x4;

#define T_TOK 65536
#define C_DIM 384
#define HD 1536
#define BE 13107
#define BP 13184

__device__ __forceinline__ u16 f2bf(float f) {
  u32 u = __float_as_uint(f);
  u32 r = (u + 0x7FFFu + ((u >> 16) & 1u)) >> 16;
  return (u16)r;
}
__device__ __forceinline__ float bf2f(u16 b) { return __uint_as_float(((u32)b) << 16); }

// RNE packed f32->bf16 pair (no builtin on gfx950)
__device__ __forceinline__ u32 cvtpk(float a, float b) {
  u32 r;
  asm("v_cvt_pk_bf16_f32 %0, %1, %2" : "=v"(r) : "v"(a), "v"(b));
  return r;
}

// async HBM->LDS DMA, 16B per lane; LDS dest = wave-uniform base + lane*16 (ours is).
__device__ __forceinline__ void gl16(const void* g, void* l) {
  __builtin_amdgcn_global_load_lds((const __attribute__((address_space(1))) void*)g,
                                   (__attribute__((address_space(3))) void*)l, 16, 0, 0);
}

// ---------------- depthwise conv 7x7 (one (n,c) plane per block) ----------------
// R8: column-stacked outputs; b32 column reads, 2 lanes/bank (free); weights off the LDS pipe.
__global__ __launch_bounds__(256) void k_conv(const float* __restrict__ x,
                                              const float* __restrict__ cw,
                                              const float* __restrict__ cb,
                                              float* __restrict__ hconv) {
  __shared__ float xp[38 * 38];  // padded plane [row 0..37][col 0..37], stride 38
  int b = blockIdx.x;            // n*384 + c
  int c = b % 384;
  int tid = threadIdx.x;
  float w49[49];
#pragma unroll
  for (int i = 0; i < 49; i++) w49[i] = cw[i * 384 + c];
  float bias = cb[c];
  for (int i = tid; i < 38 * 38; i += 256) xp[i] = 0.0f;
  __syncthreads();
  const float* xsrc = x + (size_t)b * 1024;
  {
    float4 v = *(const float4*)&xsrc[tid * 4];
    int yy = tid >> 3, xx = (tid & 7) * 4;
    float* d = &xp[(yy + 3) * 38 + xx + 3];
    d[0] = v.x; d[1] = v.y; d[2] = v.z; d[3] = v.w;
  }
  __syncthreads();
  int cl = tid & 31, r0 = (tid >> 5) << 2;
  float o0 = bias, o1 = bias, o2 = bias, o3 = bias;
  const float* colbase = &xp[r0 * 38 + cl];
#pragma unroll
  for (int kx = 0; kx < 7; kx++) {
    float v[10];
#pragma unroll
    for (int k = 0; k < 10; k++) v[k] = colbase[k * 38 + kx];
#pragma unroll
    for (int ky = 0; ky < 7; ky++) {
      float wt = w49[ky * 7 + kx];
      o0 += wt * v[ky + 0];
      o1 += wt * v[ky + 1];
      o2 += wt * v[ky + 2];
      o3 += wt * v[ky + 3];
    }
  }
  float* dst = &hconv[(size_t)b * 1024 + r0 * 32 + cl];
  dst[0] = o0;
  dst[32] = o1;
  dst[64] = o2;
  dst[96] = o3;
}

// ---------------- LayerNorm (over C) + bf16 cast ----------------
__global__ __launch_bounds__(256) void k_ln(const float* __restrict__ hconv,
                                            const float* __restrict__ lng,
                                            const float* __restrict__ lnb,
                                            u16* __restrict__ xln) {
  __shared__ float tile[384 * 33];
  int nb = blockIdx.x;              // n*32 + y
  int n = nb >> 5, y = nb & 31;
  int tid = threadIdx.x;
  const float* src = hconv + (size_t)n * 384 * 1024 + (y << 5);
  for (int i = tid; i < 12288; i += 256) {
    int c = i >> 5, w = i & 31;
    tile[c * 33 + w] = src[(size_t)c * 1024 + w];
  }
  __syncthreads();
  int wv = tid >> 6, lane = tid & 63;
  for (int w = wv; w < 32; w += 4) {
    float v[6];
    float s = 0.f, s2 = 0.f;
#pragma unroll
    for (int k = 0; k < 6; k++) {
      float t = tile[(lane + (k << 6)) * 33 + w];
      v[k] = t; s += t; s2 += t * t;
    }
#pragma unroll
    for (int off = 32; off > 0; off >>= 1) {
      s += __shfl_xor(s, off, 64);
      s2 += __shfl_xor(s2, off, 64);
    }
    float mu = s * (1.0f / 384.0f);
    float var = s2 * (1.0f / 384.0f) - mu * mu;
    float r = rsqrtf(var + 1e-6f);
    size_t t0 = ((size_t)nb << 5) + w;
#pragma unroll
    for (int k = 0; k < 6; k++) {
      int c = lane + (k << 6);
      float o = (v[k] - mu) * r * lng[c] + lnb[c];
      xln[t0 * 384 + c] = f2bf(o);
    }
  }
}

// ---------------- router: logits(8), top2 + gates; 16-bit priority key ----------------
__global__ __launch_bounds__(256) void k_router(const u16* __restrict__ xln,
                                                const float* __restrict__ gw,
                                                u32* __restrict__ keys, u32* __restrict__ vals,
                                                u32* __restrict__ topi,
                                                float* __restrict__ g1, float* __restrict__ g2) {
  __shared__ float gwl[8 * 384];
  int tid = threadIdx.x;
  for (int i = tid; i < 3072; i += 256) gwl[i] = gw[i];
  __syncthreads();
  int wv = tid >> 6, lane = tid & 63;
  int t = (blockIdx.x << 2) + wv;
  float acc[8] = {0, 0, 0, 0, 0, 0, 0, 0};
#pragma unroll
  for (int k = 0; k < 6; k++) {
    int c = lane + (k << 6);
    float xv = bf2f(xln[(size_t)t * 384 + c]);
#pragma unroll
    for (int e = 0; e < 8; e++) acc[e] += xv * gwl[e * 384 + c];
  }
#pragma unroll
  for (int off = 32; off > 0; off >>= 1) {
#pragma unroll
    for (int e = 0; e < 8; e++) acc[e] += __shfl_xor(acc[e], off, 64);
  }
  if (lane == 0) {
    float v1 = -1e30f, v2 = -1e30f;
    int e1 = 0, e2 = 0;
#pragma unroll
    for (int e = 0; e < 8; e++) {
      float l = acc[e];
      if (l > v1) { v2 = v1; e2 = e1; v1 = l; e1 = e; }
      else if (l > v2) { v2 = l; e2 = e; }
    }
    float sum = 0.f;
#pragma unroll
    for (int e = 0; e < 8; e++) sum += __expf(acc[e] - v1);
    float p = 1.0f / sum;
    float ew = __expf(v2 - v1);
    float w1 = 1.0f / (1.0f + ew);
    keys[t] = (~__float_as_uint(p)) >> 16;  // 16-bit key: ascending == descending priority
    vals[t] = (u32)t;
    topi[t] = (u32)e1 | ((u32)e2 << 8);
    g1[t] = w1;
    g2[t] = ew * w1;
  }
}

// ---------------- stable counting-sort machinery (8-bit digit) ----------------
__global__ __launch_bounds__(256) void k_hist(const u32* __restrict__ keys,
                                              u32* __restrict__ hist, int shift) {
  __shared__ u32 h[256];
  int tid = threadIdx.x;
  h[tid] = 0;
  __syncthreads();
  u32 key = keys[((size_t)blockIdx.x << 8) + tid];
  atomicAdd(&h[(key >> shift) & 255u], 1u);
  __syncthreads();
  hist[(size_t)tid * gridDim.x + blockIdx.x] = h[tid];
}

__global__ __launch_bounds__(256) void k_scan_rows(u32* __restrict__ data,
                                                   u32* __restrict__ totals, int nb) {
  __shared__ u32 ws[256];
  int d = blockIdx.x, tid = threadIdx.x;
  int seg = nb >> 8;
  u32 base = (u32)d * nb + tid * seg;
  u32 v[2] = {0, 0};
  u32 s = 0;
  for (int i = 0; i < seg; i++) { v[i] = data[base + i]; s += v[i]; }
  ws[tid] = s;
  __syncthreads();
  for (int dd = 1; dd < 256; dd <<= 1) {
    u32 t = (tid >= dd) ? ws[tid - dd] : 0u;
    __syncthreads();
    ws[tid] += t;
    __syncthreads();
  }
  if (tid == 255) totals[d] = ws[255];
  u32 run = (tid > 0) ? ws[tid - 1] : 0u;
  for (int i = 0; i < seg; i++) {
    u32 tmp = v[i];
    data[base + i] = run;
    run += tmp;
  }
}

__global__ __launch_bounds__(256) void k_scan_digits(const u32* __restrict__ totals,
                                                     u32* __restrict__ dbase) {
  __shared__ u32 ws[256];
  int tid = threadIdx.x;
  ws[tid] = totals[tid];
  __syncthreads();
  for (int dd = 1; dd < 256; dd <<= 1) {
    u32 t = (tid >= dd) ? ws[tid - dd] : 0u;
    __syncthreads();
    ws[tid] += t;
    __syncthreads();
  }
  dbase[tid] = (tid > 0) ? ws[tid - 1] : 0u;
}

__global__ __launch_bounds__(256) void k_scatter(const u32* __restrict__ kin,
                                                 const u32* __restrict__ vin,
                                                 u32* __restrict__ kout, u32* __restrict__ vout,
                                                 const u32* __restrict__ scanned,
                                                 const u32* __restrict__ dbase, int shift) {
  __shared__ u32 cnt[4 * 256];
  int tid = threadIdx.x;
  int w = tid >> 6, l = tid & 63;
  int g = (blockIdx.x << 8) + tid;
  u32 key = kin[g], val = vin[g];
  u32 d = (key >> shift) & 255u;
  for (int i = tid; i < 1024; i += 256) cnt[i] = 0u;
  __syncthreads();
  u64 match = ~0ull;
#pragma unroll
  for (int b = 0; b < 8; b++) {
    int bit = (d >> b) & 1;
    u64 bal = __ballot(bit);
    match &= bit ? bal : ~bal;
  }
  u32 rw = __popcll(match & ((1ull << l) - 1ull));
  if (rw == 0) cnt[(w << 8) + d] = (u32)__popcll(match);
  __syncthreads();
  u32 pre = 0;
  for (int w2 = 0; w2 < w; w2++) pre += cnt[(w2 << 8) + d];
  u32 pos = dbase[d] + scanned[(size_t)d * gridDim.x + blockIdx.x] + pre + rw;
  kout[pos] = key;
  vout[pos] = val;
}

__global__ __launch_bounds__(256) void k_entries(const u32* __restrict__ order,
                                                 const u32* __restrict__ topi,
                                                 const float* __restrict__ g1,
                                                 const float* __restrict__ g2,
                                                 u32* __restrict__ ee, u32* __restrict__ et,
                                                 float* __restrict__ eg) {
  int m = (blockIdx.x << 8) + threadIdx.x;
  int i = m & 65535, k = m >> 16;
  u32 tok = order[i];
  u32 pk = topi[tok];
  ee[m] = k ? ((pk >> 8) & 255u) : (pk & 255u);
  et[m] = tok;
  eg[m] = k ? g2[tok] : g1[tok];
}

__global__ __launch_bounds__(256) void k_dispatch(const u32* __restrict__ ee,
                                                  const u32* __restrict__ et,
                                                  const float* __restrict__ eg,
                                                  const u32* __restrict__ scanned,
                                                  int* __restrict__ dtok, float* __restrict__ dgate,
                                                  int* __restrict__ inv) {
  __shared__ u32 cnt[4 * 8];
  int tid = threadIdx.x;
  int w = tid >> 6, l = tid & 63;
  int m = (blockIdx.x << 8) + tid;
  u32 e = ee[m];
  if (tid < 32) cnt[tid] = 0u;
  __syncthreads();
  u64 match = ~0ull;
#pragma unroll
  for (int b = 0; b < 3; b++) {
    int bit = (e >> b) & 1;
    u64 bal = __ballot(bit);
    match &= bit ? bal : ~bal;
  }
  u32 rw = __popcll(match & ((1ull << l) - 1ull));
  if (rw == 0) cnt[(w << 3) + e] = (u32)__popcll(match);
  __syncthreads();
  u32 pre = 0;
  for (int w2 = 0; w2 < w; w2++) pre += cnt[(w2 << 3) + e];
  u32 pos = scanned[(size_t)e * gridDim.x + blockIdx.x] + pre + rw;
  if (pos < (u32)BE) {
    int slot = (int)e * BP + (int)pos;
    dtok[slot] = (int)et[m];
    dgate[slot] = eg[m];
    inv[et[m] * 2 + (m >> 16)] = slot;
  }
}

// ---------------- weight pre-pack: w [E][NKK*32][S] fp32 -> wp [e][by][kk][slot 512][8] bf16 ----
__global__ __launch_bounds__(256) void k_pack(const float* __restrict__ w,
                                              u16* __restrict__ wp, int NKK, int S) {
  __shared__ float tile[32 * 132];
  int e = blockIdx.y;
  int bx = blockIdx.x;
  int by = bx / NKK, kk = bx - by * NKK;
  int tid = threadIdx.x;
  const float* src = w + ((size_t)e * NKK * 32 + (size_t)kk * 32) * S + by * 128;
  for (int i = tid; i < 4096; i += 256) {
    int r = i >> 7, c = i & 127;
    tile[r * 132 + c] = src[(size_t)r * S + c];
  }
  __syncthreads();
  u16* dst = wp + ((size_t)e * gridDim.x + bx) * 4096;
#pragma unroll
  for (int h = 0; h < 2; h++) {
    int f = tid + (h << 8);
    int lane6 = f & 63, grp = f >> 6;
    int m15 = lane6 & 15, kq = lane6 >> 4;
    u16 o[8];
#pragma unroll
    for (int j = 0; j < 8; j++) o[j] = f2bf(tile[(kq * 8 + j) * 132 + grp * 16 + m15]);
    *(uint4*)&dst[f * 8] = *(const uint4*)o;
  }
}

// ---------------- A gather+pack for gemm1: apack [zloc][bx][kk 12][slot 512][8] ----------------
__global__ __launch_bounds__(256) void k_gather(const u16* __restrict__ xln,
                                                const int* __restrict__ dtok,
                                                u16* __restrict__ apack, int e0) {
  __shared__ int stok[128];
  int b = blockIdx.x;        // zloc*103 + bx
  int zloc = b / 103, bx = b - zloc * 103;
  int e = e0 + zloc;
  int tid = threadIdx.x;
  if (tid < 128) stok[tid] = dtok[e * BP + bx * 128 + tid];
  __syncthreads();
  u16* dst = apack + (size_t)b * 12 * 4096;
  int f0 = tid, f1 = tid + 256;
  int g0 = f0 >> 6, l0 = f0 & 63;
  int g1 = f1 >> 6, l1 = f1 & 63;
  int tokA = stok[g0 * 16 + (l0 & 15)];
  int tokB = stok[g1 * 16 + (l1 & 15)];
  const u16* sA = xln + (size_t)tokA * 384 + (l0 >> 4) * 8;
  const u16* sB = xln + (size_t)tokB * 384 + (l1 >> 4) * 8;
  u16* dA = dst + f0 * 8;
  u16* dB = dst + f1 * 8;
#pragma unroll
  for (int kk = 0; kk < 12; kk++) {
    *(uint4*)(dA + kk * 4096) = *(const uint4*)(sA + kk * 32);
    *(uint4*)(dB + kk * 4096) = *(const uint4*)(sB + kk * 32);
  }
}

// ---------------- GEMM1: hid_pack = pack(gelu(A @ w1 + b1)) ----------------
// R11/R12: LDS-broadcast staging (fragment-linear, contiguous 1KB/gl16), 3-buffer vmcnt(8) pipeline.
__global__ __launch_bounds__(256) void k_gemm1(const u16* __restrict__ apack,
                                               const u16* __restrict__ w1p,
                                               const float* __restrict__ b1,
                                               u16* __restrict__ hid, int e0) {
  __shared__ __align__(16) char smem[49152];  // 3x16KB staging; epilogue rpw aliases it
  int tid = threadIdx.x;
  int bid = blockIdx.x;
  // chunked bijective XCD swizzle (nwg=4944=8*618): z outer, bx, by fastest
  int lg = (bid & 7) * 618 + (bid >> 3);
  int z = lg / 1236;
  int rr = lg - z * 1236;
  int bx = rr / 12;
  int by = rr - bx * 12;
  int e = e0 + z;
  int wv = tid >> 6, lane = tid & 63;
  int wm = wv & 1, wn = wv >> 1;
  int quad = lane >> 4, c15 = lane & 15;
  const u16* asrc = apack + ((size_t)(z * 103 + bx) * 12) * 4096;
  const u16* bsrc = w1p + ((size_t)(e * 12 + by) * 12) * 4096;
  float4 bias4[4];
#pragma unroll
  for (int j = 0; j < 4; j++)
    bias4[j] = *(const float4*)&b1[e * HD + by * 128 + wn * 64 + j * 16 + quad * 4];
  f32x4 acc[4][4];
#pragma unroll
  for (int i = 0; i < 4; i++)
#pragma unroll
    for (int j = 0; j < 4; j++) acc[i][j] = (f32x4){0.f, 0.f, 0.f, 0.f};

  char* const bb0 = smem;
  char* const bb1 = smem + 16384;
  char* const bb2 = smem + 32768;

  // 4 gl16 per wave per tile, each contiguous 1KB (A 8KB + B 8KB unique per tile)
  auto issue = [&](int kk, char* buf) {
    short* As = (short*)buf;
    short* Bs = (short*)(buf + 8192);
    const u16* a = asrc + kk * 4096;
    const u16* b = bsrc + kk * 4096;
    gl16(a + tid * 8, &As[tid * 8]);
    gl16(a + (tid + 256) * 8, &As[(tid + 256) * 8]);
    gl16(b + tid * 8, &Bs[tid * 8]);
    gl16(b + (tid + 256) * 8, &Bs[(tid + 256) * 8]);
  };
  // swapped operands: acc[i][j] = D[m = lane&15 (token), n = quad*4+reg (w1 col)]
  auto compute = [&](char* buf) {
    short* As = (short*)buf;
    short* Bs = (short*)(buf + 8192);
    bf16x8 af[4], bfr[4];
#pragma unroll
    for (int i = 0; i < 4; i++) af[i] = *(const bf16x8*)&As[((((wm << 2) + i) << 6) | lane) * 8];
#pragma unroll
    for (int j = 0; j < 4; j++) bfr[j] = *(const bf16x8*)&Bs[((((wn << 2) + j) << 6) | lane) * 8];
    __builtin_amdgcn_s_setprio(1);
#pragma unroll
    for (int i = 0; i < 4; i++)
#pragma unroll
      for (int j = 0; j < 4; j++)
        acc[i][j] = __builtin_amdgcn_mfma_f32_16x16x32_bf16(bfr[j], af[i], acc[i][j], 0, 0, 0);
    __builtin_amdgcn_s_setprio(0);
  };

  // drain pre-loop vmem (bias loads) so in-flight vmcnt == our staging loads exactly
  asm volatile("s_waitcnt vmcnt(0) lgkmcnt(0)" ::: "memory");
  __builtin_amdgcn_sched_barrier(0);
  issue(0, bb0);
  issue(1, bb1);
#define STEP1(tt, ib, cb)                                \
  issue(tt + 2, ib);                                     \
  asm volatile("s_waitcnt vmcnt(8)" ::: "memory");       \
  __builtin_amdgcn_sched_barrier(0);                     \
  __builtin_amdgcn_s_barrier();                          \
  compute(cb);                                           \
  __builtin_amdgcn_s_barrier();
  for (int t0 = 0; t0 < 9; t0 += 3) {
    STEP1(t0, bb2, bb0)
    STEP1(t0 + 1, bb0, bb1)
    STEP1(t0 + 2, bb1, bb2)
  }
  STEP1(9, bb2, bb0)
#undef STEP1
  // t = 10 (tiles 10,11 still in flight)
  asm volatile("s_waitcnt vmcnt(4)" ::: "memory");
  __builtin_amdgcn_sched_barrier(0);
  __builtin_amdgcn_s_barrier();
  compute(bb1);
  asm volatile("s_waitcnt vmcnt(0)" ::: "memory");
  __builtin_amdgcn_sched_barrier(0);
  __builtin_amdgcn_s_barrier();
  compute(bb2);
  __syncthreads();  // all waves done reading staging; rpw may alias it

  // wave-private epilogue: bias + rcp-gelu + cvt_pk -> [64][72] repack -> pack-layout stores
  u16* prp = (u16*)smem + wv * 4608;
#pragma unroll
  for (int j = 0; j < 4; j++) {
    float4 b4 = bias4[j];
    int ncol = j * 16 + quad * 4;
#pragma unroll
    for (int i = 0; i < 4; i++) {
      int mrow = i * 16 + c15;
      float v0 = acc[i][j][0] + b4.x;
      float v1 = acc[i][j][1] + b4.y;
      float v2 = acc[i][j][2] + b4.z;
      float v3 = acc[i][j][3] + b4.w;
      v0 *= __builtin_amdgcn_rcpf(1.0f + __expf(-1.702f * v0));
      v1 *= __builtin_amdgcn_rcpf(1.0f + __expf(-1.702f * v1));
      v2 *= __builtin_amdgcn_rcpf(1.0f + __expf(-1.702f * v2));
      v3 *= __builtin_amdgcn_rcpf(1.0f + __expf(-1.702f * v3));
      uint2 pk;
      pk.x = cvtpk(v0, v1);
      pk.y = cvtpk(v2, v3);
      *(uint2*)&prp[mrow * 72 + ncol] = pk;
    }
  }
  // hid pack layout: [z][bx][kk2 48][g 8][lane 64][8]; each store = contiguous 1KB wave-write.
  u16* hb = hid + ((size_t)(z * 103 + bx) * 48 + by * 4 + wn * 2) * 4096 + (wm * 4) * 512 + lane * 8;
#pragma unroll
  for (int k2 = 0; k2 < 2; k2++)
#pragma unroll
    for (int gs = 0; gs < 4; gs++) {
      uint4 v = *(const uint4*)&prp[(gs * 16 + c15) * 72 + k2 * 32 + quad * 8];
      *(uint4*)(hb + (size_t)k2 * 4096 + gs * 512) = v;
    }
}

// ---------------- GEMM2: y = (hid @ w2 + b2) * gate (row-major bf16 out) ----------------
// R11/R12: same LDS-broadcast pipeline, 48 K-steps.
__global__ __launch_bounds__(256) void k_gemm2(const u16* __restrict__ hid,
                                               const u16* __restrict__ w2p,
                                               const float* __restrict__ b2,
                                               const float* __restrict__ dgate,
                                               u16* __restrict__ yb, int e0) {
  __shared__ __align__(16) char smem[49152];
  int tid = threadIdx.x;
  int bid = blockIdx.x;
  // bijective chunked XCD swizzle: nwg=1236, q=154, rem=4
  int xcd = bid & 7;
  int lg = xcd * 154 + (xcd < 4 ? xcd : 4) + (bid >> 3);
  int z = lg / 309;
  int rr = lg - z * 309;
  int bx = rr / 3;
  int byn = rr - bx * 3;
  int e = e0 + z;
  int wv = tid >> 6, lane = tid & 63;
  int wm = wv & 1, wn = wv >> 1;
  int quad = lane >> 4, c15 = lane & 15;
  const u16* asrc = hid + ((size_t)(z * 103 + bx) * 48) * 4096;
  const u16* bsrc = w2p + ((size_t)(e * 3 + byn) * 48) * 4096;
  float4 bias4[4];
#pragma unroll
  for (int j = 0; j < 4; j++)
    bias4[j] = *(const float4*)&b2[e * 384 + byn * 128 + wn * 64 + j * 16 + quad * 4];
  float gv[4];
#pragma unroll
  for (int i = 0; i < 4; i++) gv[i] = dgate[e * BP + bx * 128 + wm * 64 + i * 16 + c15];
  f32x4 acc[4][4];
#pragma unroll
  for (int i = 0; i < 4; i++)
#pragma unroll
    for (int j = 0; j < 4; j++) acc[i][j] = (f32x4){0.f, 0.f, 0.f, 0.f};

  char* const bb0 = smem;
  char* const bb1 = smem + 16384;
  char* const bb2 = smem + 32768;

  auto issue = [&](int kk, char* buf) {
    short* As = (short*)buf;
    short* Bs = (short*)(buf + 8192);
    const u16* a = asrc + kk * 4096;
    const u16* b = bsrc + kk * 4096;
    gl16(a + tid * 8, &As[tid * 8]);
    gl16(a + (tid + 256) * 8, &As[(tid + 256) * 8]);
    gl16(b + tid * 8, &Bs[tid * 8]);
    gl16(b + (tid + 256) * 8, &Bs[(tid + 256) * 8]);
  };
  auto compute = [&](char* buf) {
    short* As = (short*)buf;
    short* Bs = (short*)(buf + 8192);
    bf16x8 af[4], bfr[4];
#pragma unroll
    for (int i = 0; i < 4; i++) af[i] = *(const bf16x8*)&As[((((wm << 2) + i) << 6) | lane) * 8];
#pragma unroll
    for (int j = 0; j < 4; j++) bfr[j] = *(const bf16x8*)&Bs[((((wn << 2) + j) << 6) | lane) * 8];
    __builtin_amdgcn_s_setprio(1);
#pragma unroll
    for (int i = 0; i < 4; i++)
#pragma unroll
      for (int j = 0; j < 4; j++)
        acc[i][j] = __builtin_amdgcn_mfma_f32_16x16x32_bf16(bfr[j], af[i], acc[i][j], 0, 0, 0);
    __builtin_amdgcn_s_setprio(0);
  };

  asm volatile("s_waitcnt vmcnt(0) lgkmcnt(0)" ::: "memory");
  __builtin_amdgcn_sched_barrier(0);
  issue(0, bb0);
  issue(1, bb1);
#define STEP2(tt, ib, cb)                                \
  issue(tt + 2, ib);                                     \
  asm volatile("s_waitcnt vmcnt(8)" ::: "memory");       \
  __builtin_amdgcn_sched_barrier(0);                     \
  __builtin_amdgcn_s_barrier();                          \
  compute(cb);                                           \
  __builtin_amdgcn_s_barrier();
  for (int t0 = 0; t0 < 45; t0 += 3) {
    STEP2(t0, bb2, bb0)
    STEP2(t0 + 1, bb0, bb1)
    STEP2(t0 + 2, bb1, bb2)
  }
  STEP2(45, bb2, bb0)
#undef STEP2
  // t = 46 (tiles 46,47 in flight)
  asm volatile("s_waitcnt vmcnt(4)" ::: "memory");
  __builtin_amdgcn_sched_barrier(0);
  __builtin_amdgcn_s_barrier();
  compute(bb1);
  asm volatile("s_waitcnt vmcnt(0)" ::: "memory");
  __builtin_amdgcn_sched_barrier(0);
  __builtin_amdgcn_s_barrier();
  compute(bb2);
  __syncthreads();  // staging reads done; rpw may alias

  // wave-private epilogue: bias + gate -> [64][72] -> coalesced row-major stores (128B/row)
  u16* prp = (u16*)smem + wv * 4608;
#pragma unroll
  for (int j = 0; j < 4; j++) {
    float4 b4 = bias4[j];
    int ncol = j * 16 + quad * 4;
#pragma unroll
    for (int i = 0; i < 4; i++) {
      int mrow = i * 16 + c15;
      float g = gv[i];
      float v0 = (acc[i][j][0] + b4.x) * g;
      float v1 = (acc[i][j][1] + b4.y) * g;
      float v2 = (acc[i][j][2] + b4.z) * g;
      float v3 = (acc[i][j][3] + b4.w) * g;
      uint2 pk;
      pk.x = cvtpk(v0, v1);
      pk.y = cvtpk(v2, v3);
      *(uint2*)&prp[mrow * 72 + ncol] = pk;
    }
  }
  u16* ybase = yb + ((size_t)(e * BP + bx * 128 + wm * 64)) * 384 + byn * 128 + wn * 64;
#pragma unroll
  for (int it = 0; it < 8; it++) {
    int r = it * 8 + (lane >> 3);
    int n0 = (lane & 7) * 8;
    uint4 v = *(const uint4*)&prp[r * 72 + n0];
    *(uint4*)(ybase + (size_t)r * 384 + n0) = v;
  }
}

// ---------------- combine: out = x + ls * (gathered y rows), NHWC->NCHW via LDS ----------------
__global__ __launch_bounds__(256) void k_final(const float* __restrict__ x,
                                               const u16* __restrict__ yb,
                                               const int* __restrict__ inv,
                                               const float* __restrict__ ls,
                                               float* __restrict__ out) {
  __shared__ float tile[32 * 385];
  __shared__ int sl[64];
  int nb = blockIdx.x;  // n*32 + y
  int n = nb >> 5, yy = nb & 31;
  int tid = threadIdx.x;
  int t0 = nb << 5;
  if (tid < 64) sl[tid] = inv[t0 * 2 + tid];
  __syncthreads();
  for (int idx = tid; idx < 1536; idx += 256) {
    int w = idx / 48;
    int cc = (idx - w * 48) << 3;
    float a[8] = {0, 0, 0, 0, 0, 0, 0, 0};
#pragma unroll
    for (int k = 0; k < 2; k++) {
      int s = sl[(w << 1) + k];
      if (s >= 0) {
        uint4 v = *(const uint4*)&yb[(size_t)s * 384 + cc];
        const u16* pv = (const u16*)&v;
#pragma unroll
        for (int j = 0; j < 8; j++) a[j] += bf2f(pv[j]);
      }
    }
    float* tp = &tile[w * 385 + cc];
#pragma unroll
    for (int j = 0; j < 8; j++) tp[j] = a[j];
  }
  __syncthreads();
  for (int i2 = tid; i2 < 3072; i2 += 256) {
    int c = i2 >> 3, w4 = (i2 & 7) << 2;
    size_t o = ((((size_t)n * 384 + c) << 5) + yy) * 32 + w4;
    float4 xv = *(const float4*)&x[o];
    float lsv = ls[c];
    float4 r;
    r.x = xv.x + lsv * tile[(w4 + 0) * 385 + c];
    r.y = xv.y + lsv * tile[(w4 + 1) * 385 + c];
    r.z = xv.z + lsv * tile[(w4 + 2) * 385 + c];
    r.w = xv.w + lsv * tile[(w4 + 3) * 385 + c];
    *(float4*)&out[o] = r;
  }
}

extern "C" void kernel_launch(void* const* d_in, const int* in_sizes, int n_in,
                              void* d_out, int out_size, void* d_ws, size_t ws_size,
                              hipStream_t stream) {
  (void)in_sizes; (void)n_in; (void)out_size; (void)ws_size;
  const float* x     = (const float*)d_in[0];
  const float* convw = (const float*)d_in[1];
  const float* convb = (const float*)d_in[2];
  const float* lng   = (const float*)d_in[3];
  const float* lnb   = (const float*)d_in[4];
  const float* gw    = (const float*)d_in[5];
  const float* w1    = (const float*)d_in[6];
  const float* b1    = (const float*)d_in[7];
  const float* w2    = (const float*)d_in[8];
  const float* b2    = (const float*)d_in[9];
  const float* ls    = (const float*)d_in[10];
  float* out = (float*)d_out;

  char* p = (char*)d_ws;
  size_t o = 0;
  auto alloc = [&](size_t b) { void* r = p + o; o += (b + 255) & ~(size_t)255; return r; };
  u16* xln    = (u16*)alloc((size_t)T_TOK * C_DIM * 2);          // 50.3 MB
  u16* w1p    = (u16*)alloc((size_t)8 * 144 * 4096 * 2);         // 9.4 MB  [e][by12][kk12][512][8]
  u16* w2p    = (u16*)alloc((size_t)8 * 144 * 4096 * 2);         // 9.4 MB  [e][byn3][kk48][512][8]
  u16* hid    = (u16*)alloc((size_t)4 * BP * HD * 2);            // 162 MB pack layout (+conv alias)
  u16* yb     = (u16*)alloc((size_t)8 * BP * 384 * 2);           // 81 MB
  u16* apack  = (u16*)alloc((size_t)4 * 103 * 12 * 4096 * 2);    // 40.5 MB [zloc][bx][kk][512][8]
  u32* keysA  = (u32*)alloc((size_t)T_TOK * 4);
  u32* keysB  = (u32*)alloc((size_t)T_TOK * 4);
  u32* valsA  = (u32*)alloc((size_t)T_TOK * 4);
  u32* valsB  = (u32*)alloc((size_t)T_TOK * 4);
  u32* topi   = (u32*)alloc((size_t)T_TOK * 4);
  float* g1   = (float*)alloc((size_t)T_TOK * 4);
  float* g2   = (float*)alloc((size_t)T_TOK * 4);
  u32* hist   = (u32*)alloc((size_t)256 * 512 * 4);
  u32* totals = (u32*)alloc((size_t)256 * 4);
  u32* dbase  = (u32*)alloc((size_t)256 * 4);
  u32* ee     = (u32*)alloc((size_t)131072 * 4);
  u32* et     = (u32*)alloc((size_t)131072 * 4);
  float* eg   = (float*)alloc((size_t)131072 * 4);
  int* dtok   = (int*)alloc((size_t)8 * BP * 4);
  float* dgate= (float*)alloc((size_t)8 * BP * 4);
  int* inv    = (int*)alloc((size_t)T_TOK * 2 * 4);

  float* hconv = (float*)hid;  // alias: conv output consumed by k_ln before GEMM1 writes hid

  k_conv<<<24576, 256, 0, stream>>>(x, convw, convb, hconv);
  k_ln<<<2048, 256, 0, stream>>>(hconv, lng, lnb, xln);
  k_router<<<16384, 256, 0, stream>>>(xln, gw, keysA, valsA, topi, g1, g2);

  // stable radix sort on 16-bit truncated priority keys: 2 x 8-bit passes, ends back in keysA/valsA
  u32 *ki = keysA, *vi = valsA, *ko = keysB, *vo = valsB;
  for (int pass = 0; pass < 2; pass++) {
    int shift = pass * 8;
    k_hist<<<256, 256, 0, stream>>>(ki, hist, shift);
    k_scan_rows<<<256, 256, 0, stream>>>(hist, totals, 256);
    k_scan_digits<<<1, 256, 0, stream>>>(totals, dbase);
    k_scatter<<<256, 256, 0, stream>>>(ki, vi, ko, vo, hist, dbase, shift);
    u32* t1 = ki; ki = ko; ko = t1;
    u32* t2 = vi; vi = vo; vo = t2;
  }
  k_entries<<<512, 256, 0, stream>>>(vi, topi, g1, g2, ee, et, eg);
  k_hist<<<512, 256, 0, stream>>>(ee, hist, 0);
  k_scan_rows<<<256, 256, 0, stream>>>(hist, totals, 512);
  hipMemsetAsync(dtok, 0, (size_t)8 * BP * 4, stream);
  hipMemsetAsync(dgate, 0, (size_t)8 * BP * 4, stream);
  hipMemsetAsync(inv, 0xFF, (size_t)T_TOK * 2 * 4, stream);
  k_dispatch<<<512, 256, 0, stream>>>(ee, et, eg, hist, dtok, dgate, inv);

  // fragment-linear weight packs (one-time)
  k_pack<<<dim3(144, 8), 256, 0, stream>>>(w1, w1p, 12, 1536);
  k_pack<<<dim3(144, 8), 256, 0, stream>>>(w2, w2p, 48, 384);

  for (int g = 0; g < 2; g++) {
    k_gather<<<412, 256, 0, stream>>>(xln, dtok, apack, g * 4);
    k_gemm1<<<4944, 256, 0, stream>>>(apack, w1p, b1, hid, g * 4);
    k_gemm2<<<1236, 256, 0, stream>>>(hid, w2p, b2, dgate, yb, g * 4);
  }
  k_final<<<2048, 256, 0, stream>>>(x, yb, inv, ls, out);
}